// Round 6
// baseline (257.263 us; speedup 1.0000x reference)
//
#include <hip/hip_runtime.h>
#include <math.h>

#define BG   256                   // graphs
#define NN   512                   // nodes per graph
#define EPG  (NN * 16)             // 8192 edges per graph
#define NE   (BG * EPG)            // 2097152 edges
#define N0   (BG * NN)             // 131072
#define K1   256
#define N1_  (BG * K1)             // 65536
#define K2   128

__device__ __forceinline__ float4 f4fma(float s, float4 a, float4 c) {
    c.x = fmaf(s, a.x, c.x); c.y = fmaf(s, a.y, c.y);
    c.z = fmaf(s, a.z, c.z); c.w = fmaf(s, a.w, c.w);
    return c;
}

// one 64x64 GEMM tile, r16-verbatim FMA order. W read from global (L1-resident).
__device__ __forceinline__ void gemm_tile(const float* __restrict__ shx,
                                          const float4* __restrict__ W4,
                                          int row0, int rg, int cg, float4 a[4]) {
    float4 acc0 = make_float4(0.f, 0.f, 0.f, 0.f);
    float4 acc1 = acc0, acc2 = acc0, acc3 = acc0;
#pragma unroll
    for (int k4 = 0; k4 < 16; ++k4) {
        float4 xv0 = *(const float4*)&shx[(row0 + rg * 4 + 0) * 68 + k4 * 4];
        float4 xv1 = *(const float4*)&shx[(row0 + rg * 4 + 1) * 68 + k4 * 4];
        float4 xv2 = *(const float4*)&shx[(row0 + rg * 4 + 2) * 68 + k4 * 4];
        float4 xv3 = *(const float4*)&shx[(row0 + rg * 4 + 3) * 68 + k4 * 4];
        float4 wv0 = W4[(k4 * 4 + 0) * 16 + cg];
        float4 wv1 = W4[(k4 * 4 + 1) * 16 + cg];
        float4 wv2 = W4[(k4 * 4 + 2) * 16 + cg];
        float4 wv3 = W4[(k4 * 4 + 3) * 16 + cg];
        acc0 = f4fma(xv0.x, wv0, acc0); acc0 = f4fma(xv0.y, wv1, acc0);
        acc0 = f4fma(xv0.z, wv2, acc0); acc0 = f4fma(xv0.w, wv3, acc0);
        acc1 = f4fma(xv1.x, wv0, acc1); acc1 = f4fma(xv1.y, wv1, acc1);
        acc1 = f4fma(xv1.z, wv2, acc1); acc1 = f4fma(xv1.w, wv3, acc1);
        acc2 = f4fma(xv2.x, wv0, acc2); acc2 = f4fma(xv2.y, wv1, acc2);
        acc2 = f4fma(xv2.z, wv2, acc2); acc2 = f4fma(xv2.w, wv3, acc2);
        acc3 = f4fma(xv3.x, wv0, acc3); acc3 = f4fma(xv3.y, wv1, acc3);
        acc3 = f4fma(xv3.z, wv2, acc3); acc3 = f4fma(xv3.w, wv3, acc3);
    }
    a[0] = acc0; a[1] = acc1; a[2] = acc2; a[3] = acc3;
}

// ---- r17: wave-specialized megakernel (one block = one graph, 1024 thr) ----
// Waves 0-7 (t<512): CSR build (zero|atomics|scan|finalize|slots+scatter).
// Waves 8-15: x->shx stage, then 2-batch register GEMM (compute|wb pipelined).
// Segments separated by uniform __syncthreads (all threads reach each).
// pairs scatter directly to global (L2-hot, 64KB/graph); CSR metadata
// (rstl/cnt/sdinv) stays in LDS -- global rowstart/rowcnt/dinv deleted.
// Phase D (conv/hp/score/rank/readout) r16-verbatim on all 1024 threads.
template <int NPG, int K, bool REMAP, bool FINAL>
__global__ __launch_bounds__(1024)
void stage_kernel(const int* __restrict__ esrc, const int* __restrict__ edst,
                  const float* __restrict__ eatt, const int* __restrict__ nid_in,
                  int* __restrict__ nid_out, int2* __restrict__ pairs,
                  const float4* __restrict__ X4, const float4* __restrict__ W4,
                  const float4* __restrict__ b4, const float4* __restrict__ wp4,
                  const float* __restrict__ bp,
                  float4* __restrict__ xn4, float* __restrict__ xr,
                  const float* __restrict__ x1r, float* __restrict__ out) {
    constexpr int PASSES = NPG / 32;
    constexpr int LPN = 1024 / NPG;          // 2 (stage1) or 4 (stage2)
    constexpr int LOG_LPN = (LPN == 2) ? 1 : 2;
    constexpr int QF = 16 / LPN;
    constexpr int RLOG = (NPG == 512) ? 9 : 8;
    constexpr int RCH = NPG * NPG / 1024;
    constexpr int SH_A = NPG * 68;
    constexpr int TILES = NPG / 64, TPP = TILES / 2, TB = TPP / 2 ? TPP / 2 : 1;
    __shared__ __align__(16) float smem[SH_A + 4096 + 2 * NPG];
    float* shx = smem;
    float* S   = smem + SH_A;                // scratch region
    int*   cnt   = (int*)S;                  // [NPG] rowcnt (persists to D)
    int*   rstl  = (int*)S + NPG;            // [NPG] local rowstart
    float* sdinv = S + 2 * NPG;              // [NPG]
    int*   perm  = (int*)S + 3 * NPG;        // [NPG] (phase D)
    float* shp   = S + 4 * NPG;              // [NPG] == scn (dead after seg4)
    int*   scn   = (int*)S + 4 * NPG;
    float* wsum  = S + 5 * NPG;              // [NPG] (dead after seg3)
    float* sbw   = S + 6 * NPG;              // [64]
    int*   hist  = (int*)S + 6 * NPG + 64;   // [64]
    int*   wtot  = (int*)S + 6 * NPG + 128;  // [8]
    float4* smx  = (float4*)S;               // readout overlay [0,2048)
    float4* ssm  = (float4*)(S + 2048);      //                 [2048,4096)
    float* ssc   = S + 4096;                 // [NPG] live through readout
    int*   rnk   = (int*)S + 4096 + NPG;     // [NPG] live through readout

    int g = blockIdx.x, nbase = g * NPG, e0 = g * EPG;
    int t = threadIdx.x;
    int lane16 = t & 15, lane = t & 63;

    int ed[16], es[16]; float ea[16];        // CSR-path regs
    int xs = 0, xval = 0;
    float4 accA[TB][4], accB[TB][4];         // GEMM-path regs
    int tl = t - 512, q2 = (t & 511) >> 8, tq = t & 255;
    int rgg = tq >> 4, cgg = tq & 15;

    // ---- seg0: CSR zero+edge-load  ||  LD x-stage + small inits ----
    if (t < 512) {
        for (int i = t; i < NPG; i += 512) { cnt[i] = 0; wsum[i] = 0.f; }
        const int4*   edst4 = (const int4*)(edst + e0);
        const int4*   esrc4 = (const int4*)(esrc + e0);
        const float4* eatt4 = (const float4*)(eatt + e0);
#pragma unroll
        for (int c = 0; c < 4; ++c) {
            int ch = t + c * 512;
            int4   dd = edst4[ch];
            int4   ss = esrc4[ch];
            float4 ww = eatt4[ch];
            ed[c * 4 + 0] = dd.x; ed[c * 4 + 1] = dd.y; ed[c * 4 + 2] = dd.z; ed[c * 4 + 3] = dd.w;
            es[c * 4 + 0] = ss.x; es[c * 4 + 1] = ss.y; es[c * 4 + 2] = ss.z; es[c * 4 + 3] = ss.w;
            ea[c * 4 + 0] = ww.x; ea[c * 4 + 1] = ww.y; ea[c * 4 + 2] = ww.z; ea[c * 4 + 3] = ww.w;
        }
        if (REMAP) {
#pragma unroll
            for (int j = 0; j < 16; ++j) { ed[j] = nid_in[ed[j]]; es[j] = nid_in[es[j]]; }
        }
    } else {
        for (int i = tl; i < NPG * 16; i += 512) {
            int r = i >> 4, c4 = i & 15;
            *(float4*)&shx[r * 68 + c4 * 4] = X4[(size_t)nbase * 16 + i];
        }
        if (tl < 64) { sbw[tl] = ((const float*)b4)[tl]; hist[tl] = 0; }
        for (int i = tl; i < NPG; i += 512) rnk[i] = 0;
    }
    __syncthreads();
    // ---- seg1: CSR count atomics  ||  LD GEMM batch A compute ----
    if (t < 512) {
#pragma unroll
        for (int j = 0; j < 16; ++j) {
            bool valid = !REMAP || (ed[j] >= 0 && es[j] >= 0);
            if (valid) {
                int dl = ed[j] - nbase;
                atomicAdd(&cnt[dl], 1);
                atomicAdd(&wsum[dl], ea[j]);
            }
        }
    } else {
#pragma unroll
        for (int b = 0; b < TB; ++b)
            gemm_tile(shx, W4, (q2 * TPP + b) * 64, rgg, cgg, accA[b]);
    }
    __syncthreads();
    // ---- seg2: CSR per-wave scan  ||  LD write back batch A ----
    if (t < 512) {
        int wvid = t >> 6;
        xval = (t < NPG) ? cnt[t] : 0;
        xs = xval;
#pragma unroll
        for (int off = 1; off < 64; off <<= 1) {
            int v = __shfl_up(xs, off, 64);
            if (lane >= off) xs += v;
        }
        if (lane == 63) wtot[wvid] = xs;
    } else {
#pragma unroll
        for (int b = 0; b < TB; ++b) {
            int row0 = (q2 * TPP + b) * 64;
            *(float4*)&shx[(row0 + rgg * 4 + 0) * 68 + cgg * 4] = accA[b][0];
            *(float4*)&shx[(row0 + rgg * 4 + 1) * 68 + cgg * 4] = accA[b][1];
            *(float4*)&shx[(row0 + rgg * 4 + 2) * 68 + cgg * 4] = accA[b][2];
            *(float4*)&shx[(row0 + rgg * 4 + 3) * 68 + cgg * 4] = accA[b][3];
        }
    }
    __syncthreads();
    // ---- seg3: CSR finalize rows  ||  LD GEMM batch B compute ----
    if (t < 512) {
        int wvid = t >> 6;
        int woff = 0;
#pragma unroll
        for (int w = 0; w < 8; ++w) { int wt = wtot[w]; if (w < wvid) woff += wt; }
        xs += woff;                          // inclusive scan
        if (t < NPG) {
            int st = xs - xval;              // exclusive
            rstl[t] = st;
            sdinv[t] = rsqrtf(wsum[t] + 1.0f);
            scn[t] = st;
        }
    } else {
#pragma unroll
        for (int b = 0; b < TB; ++b)
            gemm_tile(shx, W4, (q2 * TPP + TB + b) * 64, rgg, cgg, accB[b]);
    }
    __syncthreads();
    // ---- seg4: CSR slots + scatter pairs  ||  LD write back batch B ----
    if (t < 512) {
#pragma unroll
        for (int j = 0; j < 16; ++j) {
            bool valid = !REMAP || (ed[j] >= 0 && es[j] >= 0);
            if (valid) {
                int dl = ed[j] - nbase, sl = es[j] - nbase;
                float cf = sdinv[dl] * ea[j] * sdinv[sl];
                int slot = atomicAdd(&scn[dl], 1);
                pairs[e0 + slot] = make_int2(sl, __float_as_int(cf));
            }
        }
    } else {
#pragma unroll
        for (int b = 0; b < TB; ++b) {
            int row0 = (q2 * TPP + TB + b) * 64;
            *(float4*)&shx[(row0 + rgg * 4 + 0) * 68 + cgg * 4] = accB[b][0];
            *(float4*)&shx[(row0 + rgg * 4 + 1) * 68 + cgg * 4] = accB[b][1];
            *(float4*)&shx[(row0 + rgg * 4 + 2) * 68 + cgg * 4] = accB[b][2];
            *(float4*)&shx[(row0 + rgg * 4 + 3) * 68 + cgg * 4] = accB[b][3];
        }
    }
    __syncthreads();

    // ================= phase D (r16-verbatim, metadata from LDS) =========
    for (int i = t; i < NPG; i += 1024) {
        int c = min(cnt[i], 63);
        atomicAdd(&hist[c], 1);
    }
    __syncthreads();
    if (t < 64) {
        int v = hist[t], s = v;
#pragma unroll
        for (int off = 1; off < 64; off <<= 1) {
            int u = __shfl_up(s, off, 64);
            if (lane >= off) s += u;
        }
        hist[t] = s - v;
    }
    __syncthreads();
    for (int i = t; i < NPG; i += 1024) {
        int c = min(cnt[i], 63);
        int pos = atomicAdd(&hist[c], 1);
        perm[pos] = i;                       // sorted by degree -> lanes
    }
    __syncthreads();
    // conv, LPN lanes per node (r12 shape, depth-2 prefetch)
    {
        int idx2 = t >> LOG_LPN;
        int half = t & (LPN - 1);
        int nl = perm[idx2];
        int st = rstl[nl], cn = cnt[nl];
        float di = sdinv[nl], dii = di * di;
        const int2* pb = pairs + e0 + st;
        int fb = half * QF;
        float4 acc[QF];
#pragma unroll
        for (int c = 0; c < QF; ++c) {
            float4 xv = *(const float4*)&shx[nl * 68 + (fb + c) * 4];
            acc[c].x = fmaf(xv.x, dii, sbw[(fb + c) * 4 + 0]);
            acc[c].y = fmaf(xv.y, dii, sbw[(fb + c) * 4 + 1]);
            acc[c].z = fmaf(xv.z, dii, sbw[(fb + c) * 4 + 2]);
            acc[c].w = fmaf(xv.w, dii, sbw[(fb + c) * 4 + 3]);
        }
        int2 p0 = (cn > 0) ? pb[0] : make_int2(0, 0);
        int2 p1 = (cn > 1) ? pb[1] : make_int2(0, 0);
        for (int j = 0; j < cn; ++j) {
            int2 p2 = (j + 2 < cn) ? pb[j + 2] : make_int2(0, 0);
            float cfv = __int_as_float(p0.y);
            int   s   = p0.x;
#pragma unroll
            for (int c = 0; c < QF; ++c)
                acc[c] = f4fma(cfv, *(const float4*)&shx[s * 68 + (fb + c) * 4], acc[c]);
            p0 = p1; p1 = p2;
        }
#pragma unroll
        for (int c = 0; c < QF; ++c) {
            acc[c].x = fmaxf(acc[c].x, 0.f); acc[c].y = fmaxf(acc[c].y, 0.f);
            acc[c].z = fmaxf(acc[c].z, 0.f); acc[c].w = fmaxf(acc[c].w, 0.f);
        }
        __syncthreads();                     // all conv reads of hx complete
#pragma unroll
        for (int c = 0; c < QF; ++c)
            *(float4*)&shx[nl * 68 + (fb + c) * 4] = acc[c];   // h over hx
    }
    __syncthreads();
    // hp = h . Wp
    if (t < 512) {
        int wv8 = t >> 6, sub4 = (t >> 4) & 3;
        float4 w4 = wp4[lane16];
#pragma unroll
        for (int p = 0; p < PASSES; ++p) {
            int n2 = p * 32 + wv8 * 4 + sub4;
            float4 a = *(const float4*)&shx[n2 * 68 + lane16 * 4];
            float tt = a.x * w4.x + a.y * w4.y + a.z * w4.z + a.w * w4.w;
            tt += __shfl_xor(tt, 1, 64); tt += __shfl_xor(tt, 2, 64);
            tt += __shfl_xor(tt, 4, 64); tt += __shfl_xor(tt, 8, 64);
            if (lane16 == 0) shp[n2] = tt;
        }
    }
    __syncthreads();
    // score conv
    if (t < NPG) {
        int i = perm[t];
        int st = rstl[i], cn = cnt[i];
        float di = sdinv[i];
        const int2* pb = pairs + e0 + st;
        float a = fmaf(shp[i], di * di, bp[0]);
        int2 q0 = (cn > 0) ? pb[0] : make_int2(0, 0);
        int2 q1 = (cn > 1) ? pb[1] : make_int2(0, 0);
        for (int j = 0; j < cn; ++j) {
            int2 q2v = (j + 2 < cn) ? pb[j + 2] : make_int2(0, 0);
            a = fmaf(__int_as_float(q0.y), shp[q0.x], a);
            q0 = q1; q1 = q2v;
        }
        ssc[i] = a;
    }
    __syncthreads();
    // exact top-k rank (split partials)
    {
        int part = t >> RLOG;
        int i = t & (NPG - 1);
        float si = ssc[i];
        int j0 = part * RCH;
        int rank = 0;
        for (int j = j0; j < j0 + RCH; j += 4) {
            float4 sj = *(const float4*)&ssc[j];
            rank += (sj.x > si) || (sj.x == si && j     < i);
            rank += (sj.y > si) || (sj.y == si && j + 1 < i);
            rank += (sj.z > si) || (sj.z == si && j + 2 < i);
            rank += (sj.w > si) || (sj.w == si && j + 3 < i);
        }
        atomicAdd(&rnk[i], rank);
    }
    __syncthreads();
    if (!FINAL)
        for (int i = t; i < NPG; i += 1024)
            nid_out[nbase + i] = (rnk[i] < K) ? (g * K + rnk[i]) : -1;
    // gated xn write + readout partials
    float4 mx = make_float4(-3.402823466e38f, -3.402823466e38f, -3.402823466e38f, -3.402823466e38f);
    float4 sm = make_float4(0.f, 0.f, 0.f, 0.f);
    if (t < 512) {
        int wv8 = t >> 6, sub4 = (t >> 4) & 3;
#pragma unroll
        for (int p = 0; p < PASSES; ++p) {
            int n2 = p * 32 + wv8 * 4 + sub4;
            int r = rnk[n2];
            if (r < K) {
                float gt = tanhf(ssc[n2]);
                float4 v = *(const float4*)&shx[n2 * 68 + lane16 * 4];
                v.x *= gt; v.y *= gt; v.z *= gt; v.w *= gt;
                if (!FINAL) xn4[((size_t)g * K + r) * 16 + lane16] = v;
                mx.x = fmaxf(mx.x, v.x); mx.y = fmaxf(mx.y, v.y);
                mx.z = fmaxf(mx.z, v.z); mx.w = fmaxf(mx.w, v.w);
                sm.x += v.x; sm.y += v.y; sm.z += v.z; sm.w += v.w;
            }
        }
    }
    int grp = t >> 4;
    __syncthreads();                         // scratch dead; smx/ssm overlay safe
    if (t < 512) {
        smx[grp * 16 + lane16] = mx;
        ssm[grp * 16 + lane16] = sm;
    }
    __syncthreads();
    if (grp == 0) {
#pragma unroll
        for (int u = 1; u < 32; ++u) {
            float4 a = smx[u * 16 + lane16], b = ssm[u * 16 + lane16];
            mx.x = fmaxf(mx.x, a.x); mx.y = fmaxf(mx.y, a.y);
            mx.z = fmaxf(mx.z, a.z); mx.w = fmaxf(mx.w, a.w);
            sm.x += b.x; sm.y += b.y; sm.z += b.z; sm.w += b.w;
        }
        float invK = 1.f / K;
        int c = lane16 * 4;
        float mr[4] = {mx.x, mx.y, mx.z, mx.w};
        float ar[4] = {sm.x * invK, sm.y * invK, sm.z * invK, sm.w * invK};
#pragma unroll
        for (int u = 0; u < 4; ++u) {
            if (FINAL) {
                out[g * 128 + c + u]      = 0.5f * (x1r[g * 128 + c + u]      + mr[u]);
                out[g * 128 + 64 + c + u] = 0.5f * (x1r[g * 128 + 64 + c + u] + ar[u]);
            } else {
                xr[g * 128 + c + u]      = mr[u];
                xr[g * 128 + 64 + c + u] = ar[u];
            }
        }
    }
}

extern "C" void kernel_launch(void* const* d_in, const int* in_sizes, int n_in,
                              void* d_out, int out_size, void* d_ws, size_t ws_size,
                              hipStream_t stream) {
    const float* x    = (const float*)d_in[0];
    const float* eatt = (const float*)d_in[1];
    const float* W1   = (const float*)d_in[2];
    const float* b1   = (const float*)d_in[3];
    const float* Wp1  = (const float*)d_in[4];
    const float* bp1  = (const float*)d_in[5];
    const float* W2   = (const float*)d_in[6];
    const float* b2   = (const float*)d_in[7];
    const float* Wp2  = (const float*)d_in[8];
    const float* bp2  = (const float*)d_in[9];
    const int*   esrc = (const int*)d_in[10];
    const int*   edst = (const int*)d_in[11];
    float* out = (float*)d_out;

    float* ws = (float*)d_ws;
    size_t o = 0;
    float* A    = ws + o; o += (size_t)N0 * 64;   // unused (kept layout)
    float* xn1  = ws + o; o += (size_t)N1_ * 64;
    int2*  prs  = (int2*)(ws + o); o += (size_t)NE * 2;
    int*   rst  = (int*)(ws + o); o += N0;        // unused
    int*   rcn  = (int*)(ws + o); o += N0;        // unused
    float* dinv = ws + o; o += N0;                // unused
    int*   nid  = (int*)(ws + o); o += N0;
    float* x1r  = ws + o; o += BG * 128;
    (void)A; (void)rst; (void)rcn; (void)dinv;

    // ---- stage 1: specialized CSR || x-stage+GEMM, then fused tail ----
    stage_kernel<NN, K1, false, false><<<BG, 1024, 0, stream>>>(
        esrc, edst, eatt, nullptr, nid, prs,
        (const float4*)x, (const float4*)W1, (const float4*)b1,
        (const float4*)Wp1, bp1, (float4*)xn1, x1r, nullptr, nullptr);
    // ---- stage 2: same with remap + final readout ----
    stage_kernel<K1, K2, true, true><<<BG, 1024, 0, stream>>>(
        esrc, edst, eatt, nid, nullptr, prs,
        (const float4*)xn1, (const float4*)W2, (const float4*)b2,
        (const float4*)Wp2, bp2, nullptr, nullptr, x1r, out);
}

// Round 7
// 209.871 us; speedup vs baseline: 1.2258x; 1.2258x over previous
//
#include <hip/hip_runtime.h>
#include <math.h>

#define BG   256                   // graphs
#define NN   512                   // nodes per graph
#define EPG  (NN * 16)             // 8192 edges per graph
#define NE   (BG * EPG)            // 2097152 edges

__device__ __forceinline__ float4 f4fma(float s, float4 a, float4 c) {
    c.x = fmaf(s, a.x, c.x); c.y = fmaf(s, a.y, c.y);
    c.z = fmaf(s, a.z, c.z); c.w = fmaf(s, a.w, c.w);
    return c;
}

// one 64x64 GEMM tile, r16-verbatim FMA order. W from global (L1-resident).
__device__ __forceinline__ void gemm_tile(const float* __restrict__ shx,
                                          const float4* __restrict__ W4,
                                          int row0, int rg, int cg, float4 a[4]) {
    float4 acc0 = make_float4(0.f, 0.f, 0.f, 0.f);
    float4 acc1 = acc0, acc2 = acc0, acc3 = acc0;
#pragma unroll
    for (int k4 = 0; k4 < 16; ++k4) {
        float4 xv0 = *(const float4*)&shx[(row0 + rg * 4 + 0) * 68 + k4 * 4];
        float4 xv1 = *(const float4*)&shx[(row0 + rg * 4 + 1) * 68 + k4 * 4];
        float4 xv2 = *(const float4*)&shx[(row0 + rg * 4 + 2) * 68 + k4 * 4];
        float4 xv3 = *(const float4*)&shx[(row0 + rg * 4 + 3) * 68 + k4 * 4];
        float4 wv0 = W4[(k4 * 4 + 0) * 16 + cg];
        float4 wv1 = W4[(k4 * 4 + 1) * 16 + cg];
        float4 wv2 = W4[(k4 * 4 + 2) * 16 + cg];
        float4 wv3 = W4[(k4 * 4 + 3) * 16 + cg];
        acc0 = f4fma(xv0.x, wv0, acc0); acc0 = f4fma(xv0.y, wv1, acc0);
        acc0 = f4fma(xv0.z, wv2, acc0); acc0 = f4fma(xv0.w, wv3, acc0);
        acc1 = f4fma(xv1.x, wv0, acc1); acc1 = f4fma(xv1.y, wv1, acc1);
        acc1 = f4fma(xv1.z, wv2, acc1); acc1 = f4fma(xv1.w, wv3, acc1);
        acc2 = f4fma(xv2.x, wv0, acc2); acc2 = f4fma(xv2.y, wv1, acc2);
        acc2 = f4fma(xv2.z, wv2, acc2); acc2 = f4fma(xv2.w, wv3, acc2);
        acc3 = f4fma(xv3.x, wv0, acc3); acc3 = f4fma(xv3.y, wv1, acc3);
        acc3 = f4fma(xv3.z, wv2, acc3); acc3 = f4fma(xv3.w, wv3, acc3);
    }
    a[0] = acc0; a[1] = acc1; a[2] = acc2; a[3] = acc3;
}

// ---- r18: SINGLE megakernel, one block = one graph, both stages. ----
// Stage1->stage2 dataflow is block-local: xn/nid/x1r never leave LDS.
// Stage1 pairs: LDS-staged coalesced global write (r17 lesson: direct
// scatter = 139MB write amplification). Stage2 pairs: live in LDS rows
// 256-511 of shx (dead after compact), never touch global.
__global__ __launch_bounds__(1024)
void mega_kernel(const int* __restrict__ esrc, const int* __restrict__ edst,
                 const float* __restrict__ eatt, int2* __restrict__ pairs,
                 const float4* __restrict__ X4,
                 const float4* __restrict__ W1_4, const float4* __restrict__ b1_4,
                 const float4* __restrict__ wp1_4, const float* __restrict__ bp1,
                 const float4* __restrict__ W2_4, const float4* __restrict__ b2_4,
                 const float4* __restrict__ wp2_4, const float* __restrict__ bp2,
                 float* __restrict__ out) {
    // LDS: shx 34816 + scratch 5904 = 40720 floats = 162880 B
    __shared__ __align__(16) float smem[40720];
    float* shx  = smem;                           // [512*68]
    float* S    = smem + 34816;
    int*   cnt   = (int*)S;                       // [512]
    int*   rstl  = (int*)S + 512;                 // [512]
    float* sdinv = S + 1024;                      // [512]
    int*   perm  = (int*)S + 1536;                // [512]  (alias: nor)
    int*   scn   = (int*)S + 2048;                // [512]  (alias: shp)
    float* shp   = S + 2048;
    float* wsum  = S + 2560;                      // [512]  (alias: ssc)
    float* ssc   = S + 2560;
    int*   rnk   = (int*)S + 3072;                // [512]
    float* sbw   = S + 3584;                      // [64]
    int*   hist  = (int*)S + 3648;                // [64]
    int*   wtot  = (int*)S + 3712;                // [16]
    float* x1rs  = S + 3728;                      // [128]
    float4* redx = (float4*)(S + 3856);           // [32*16] f4 (2-pass reduce)

    int g = blockIdx.x, nb1 = g * NN, e0 = g * EPG;
    int t = threadIdx.x;
    int lane16 = t & 15, lane = t & 63;

    // ================= STAGE 1 =================
    // ---- CSR1 (lpair overlays shx[0:8192) -- x not staged yet) ----
    for (int i = t; i < NN; i += 1024) { cnt[i] = 0; wsum[i] = 0.f; }
    __syncthreads();
    {
        const int4*   edst4 = (const int4*)(edst + e0);
        const int4*   esrc4 = (const int4*)(esrc + e0);
        const float4* eatt4 = (const float4*)(eatt + e0);
        int ed[8], es[8]; float ea[8];
#pragma unroll
        for (int c = 0; c < 2; ++c) {
            int ch = t + c * 1024;
            int4 dd = edst4[ch]; int4 ss = esrc4[ch]; float4 ww = eatt4[ch];
            ed[c*4+0]=dd.x; ed[c*4+1]=dd.y; ed[c*4+2]=dd.z; ed[c*4+3]=dd.w;
            es[c*4+0]=ss.x; es[c*4+1]=ss.y; es[c*4+2]=ss.z; es[c*4+3]=ss.w;
            ea[c*4+0]=ww.x; ea[c*4+1]=ww.y; ea[c*4+2]=ww.z; ea[c*4+3]=ww.w;
        }
#pragma unroll
        for (int j = 0; j < 8; ++j) {
            int dl = ed[j] - nb1;
            atomicAdd(&cnt[dl], 1);
            atomicAdd(&wsum[dl], ea[j]);
        }
        __syncthreads();
        int wv = t >> 6;
        int xval = (t < NN) ? cnt[t] : 0;
        int xs = xval;
#pragma unroll
        for (int off = 1; off < 64; off <<= 1) {
            int v = __shfl_up(xs, off, 64);
            if (lane >= off) xs += v;
        }
        if (lane == 63) wtot[wv] = xs;
        __syncthreads();
        int woff = 0;
#pragma unroll
        for (int w = 0; w < 16; ++w) { int wt = wtot[w]; if (w < wv) woff += wt; }
        xs += woff;
        if (t < NN) {
            int st = xs - xval;
            rstl[t] = st;
            sdinv[t] = rsqrtf(wsum[t] + 1.0f);
            scn[t] = st;
        }
        __syncthreads();
        int slots[8]; float cf[8];
#pragma unroll
        for (int j = 0; j < 8; ++j) {
            int dl = ed[j] - nb1, sl = es[j] - nb1;
            cf[j] = sdinv[dl] * ea[j] * sdinv[sl];
            slots[j] = atomicAdd(&scn[dl], 1);
        }
        int2* lp = (int2*)smem;
#pragma unroll
        for (int j = 0; j < 8; ++j)
            if (slots[j] < 4096)
                lp[slots[j]] = make_int2(es[j] - nb1, __float_as_int(cf[j]));
        __syncthreads();
        for (int k = t; k < 4096; k += 1024) pairs[e0 + k] = lp[k];
        __syncthreads();
#pragma unroll
        for (int j = 0; j < 8; ++j)
            if (slots[j] >= 4096)
                lp[slots[j] - 4096] = make_int2(es[j] - nb1, __float_as_int(cf[j]));
        __syncthreads();
        for (int k = t; k < 4096; k += 1024) pairs[e0 + 4096 + k] = lp[k];
        __syncthreads();
    }
    // ---- stage x + inits ----
    for (int i = t; i < NN * 16; i += 1024) {
        int r = i >> 4, c4 = i & 15;
        *(float4*)&shx[r * 68 + c4 * 4] = X4[(size_t)nb1 * 16 + i];
    }
    if (t < 64) { sbw[t] = ((const float*)b1_4)[t]; hist[t] = 0; }
    for (int i = t; i < NN; i += 1024) rnk[i] = 0;
    __syncthreads();
    // ---- GEMM1 (8 tiles, r16 order) ----
    {
        int q = t >> 8, tq = t & 255, rg = tq >> 4, cg = tq & 15;
        float4 ac[2][4];
#pragma unroll
        for (int tt = 0; tt < 2; ++tt)
            gemm_tile(shx, W1_4, (tt * 4 + q) * 64, rg, cg, ac[tt]);
        __syncthreads();
#pragma unroll
        for (int tt = 0; tt < 2; ++tt) {
            int row0 = (tt * 4 + q) * 64;
            *(float4*)&shx[(row0 + rg * 4 + 0) * 68 + cg * 4] = ac[tt][0];
            *(float4*)&shx[(row0 + rg * 4 + 1) * 68 + cg * 4] = ac[tt][1];
            *(float4*)&shx[(row0 + rg * 4 + 2) * 68 + cg * 4] = ac[tt][2];
            *(float4*)&shx[(row0 + rg * 4 + 3) * 68 + cg * 4] = ac[tt][3];
        }
    }
    __syncthreads();
    // ---- tail1: hist/perm ----
    for (int i = t; i < NN; i += 1024) atomicAdd(&hist[min(cnt[i], 63)], 1);
    __syncthreads();
    if (t < 64) {
        int v = hist[t], s = v;
#pragma unroll
        for (int off = 1; off < 64; off <<= 1) {
            int u = __shfl_up(s, off, 64);
            if (lane >= off) s += u;
        }
        hist[t] = s - v;
    }
    __syncthreads();
    for (int i = t; i < NN; i += 1024) {
        int pos = atomicAdd(&hist[min(cnt[i], 63)], 1);
        perm[pos] = i;
    }
    __syncthreads();
    // ---- conv1 (LPN=2, QF=8, r16-verbatim) ----
    {
        int idx2 = t >> 1, half = t & 1, fb = half * 8;
        int nl = perm[idx2];
        int st = rstl[nl], cn = cnt[nl];
        float di = sdinv[nl], dii = di * di;
        const int2* pb = pairs + e0 + st;
        float4 acc[8];
#pragma unroll
        for (int c = 0; c < 8; ++c) {
            float4 xv = *(const float4*)&shx[nl * 68 + (fb + c) * 4];
            acc[c].x = fmaf(xv.x, dii, sbw[(fb + c) * 4 + 0]);
            acc[c].y = fmaf(xv.y, dii, sbw[(fb + c) * 4 + 1]);
            acc[c].z = fmaf(xv.z, dii, sbw[(fb + c) * 4 + 2]);
            acc[c].w = fmaf(xv.w, dii, sbw[(fb + c) * 4 + 3]);
        }
        int2 p0 = (cn > 0) ? pb[0] : make_int2(0, 0);
        int2 p1 = (cn > 1) ? pb[1] : make_int2(0, 0);
        for (int j = 0; j < cn; ++j) {
            int2 p2 = (j + 2 < cn) ? pb[j + 2] : make_int2(0, 0);
            float cfv = __int_as_float(p0.y);
            int   s   = p0.x;
#pragma unroll
            for (int c = 0; c < 8; ++c)
                acc[c] = f4fma(cfv, *(const float4*)&shx[s * 68 + (fb + c) * 4], acc[c]);
            p0 = p1; p1 = p2;
        }
#pragma unroll
        for (int c = 0; c < 8; ++c) {
            acc[c].x = fmaxf(acc[c].x, 0.f); acc[c].y = fmaxf(acc[c].y, 0.f);
            acc[c].z = fmaxf(acc[c].z, 0.f); acc[c].w = fmaxf(acc[c].w, 0.f);
        }
        __syncthreads();
#pragma unroll
        for (int c = 0; c < 8; ++c)
            *(float4*)&shx[nl * 68 + (fb + c) * 4] = acc[c];
    }
    __syncthreads();
    // ---- hp1 ----
    if (t < 512) {
        int wv8 = t >> 6, sub4 = (t >> 4) & 3;
        float4 w4 = wp1_4[lane16];
#pragma unroll
        for (int p = 0; p < 16; ++p) {
            int n2 = p * 32 + wv8 * 4 + sub4;
            float4 a = *(const float4*)&shx[n2 * 68 + lane16 * 4];
            float tt = a.x * w4.x + a.y * w4.y + a.z * w4.z + a.w * w4.w;
            tt += __shfl_xor(tt, 1, 64); tt += __shfl_xor(tt, 2, 64);
            tt += __shfl_xor(tt, 4, 64); tt += __shfl_xor(tt, 8, 64);
            if (lane16 == 0) shp[n2] = tt;
        }
    }
    __syncthreads();
    // ---- score1 ----
    if (t < NN) {
        int i = perm[t];
        int st = rstl[i], cn = cnt[i];
        float di = sdinv[i];
        const int2* pb = pairs + e0 + st;
        float a = fmaf(shp[i], di * di, bp1[0]);
        int2 q0 = (cn > 0) ? pb[0] : make_int2(0, 0);
        int2 q1 = (cn > 1) ? pb[1] : make_int2(0, 0);
        for (int j = 0; j < cn; ++j) {
            int2 q2v = (j + 2 < cn) ? pb[j + 2] : make_int2(0, 0);
            a = fmaf(__int_as_float(q0.y), shp[q0.x], a);
            q0 = q1; q1 = q2v;
        }
        ssc[i] = a;
    }
    __syncthreads();
    // ---- rank1 (2 partials per node) ----
    {
        int part = t >> 9, i = t & 511;
        float si = ssc[i];
        int j0 = part * 256, rank = 0;
        for (int j = j0; j < j0 + 256; j += 4) {
            float4 sj = *(const float4*)&ssc[j];
            rank += (sj.x > si) || (sj.x == si && j     < i);
            rank += (sj.y > si) || (sj.y == si && j + 1 < i);
            rank += (sj.z > si) || (sj.z == si && j + 2 < i);
            rank += (sj.w > si) || (sj.w == si && j + 3 < i);
        }
        atomicAdd(&rnk[i], rank);
    }
    __syncthreads();
    // ---- readout1 -> x1rs (r16 order; 2-pass 8KB reduce) ----
    {
        float4 mx = make_float4(-3.402823466e38f, -3.402823466e38f, -3.402823466e38f, -3.402823466e38f);
        float4 sm = make_float4(0.f, 0.f, 0.f, 0.f);
        if (t < 512) {
            int wv8 = t >> 6, sub4 = (t >> 4) & 3;
#pragma unroll
            for (int p = 0; p < 16; ++p) {
                int n2 = p * 32 + wv8 * 4 + sub4;
                int r = rnk[n2];
                if (r < 256) {
                    float gt = tanhf(ssc[n2]);
                    float4 v = *(const float4*)&shx[n2 * 68 + lane16 * 4];
                    v.x *= gt; v.y *= gt; v.z *= gt; v.w *= gt;
                    mx.x = fmaxf(mx.x, v.x); mx.y = fmaxf(mx.y, v.y);
                    mx.z = fmaxf(mx.z, v.z); mx.w = fmaxf(mx.w, v.w);
                    sm.x += v.x; sm.y += v.y; sm.z += v.z; sm.w += v.w;
                }
            }
        }
        int grp = t >> 4;
        __syncthreads();
        if (t < 512) redx[grp * 16 + lane16] = mx;
        __syncthreads();
        float mr[4] = {0, 0, 0, 0};
        if (grp == 0) {
#pragma unroll
            for (int u = 1; u < 32; ++u) {
                float4 a = redx[u * 16 + lane16];
                mx.x = fmaxf(mx.x, a.x); mx.y = fmaxf(mx.y, a.y);
                mx.z = fmaxf(mx.z, a.z); mx.w = fmaxf(mx.w, a.w);
            }
            mr[0] = mx.x; mr[1] = mx.y; mr[2] = mx.z; mr[3] = mx.w;
        }
        __syncthreads();
        if (t < 512) redx[grp * 16 + lane16] = sm;
        __syncthreads();
        if (grp == 0) {
#pragma unroll
            for (int u = 1; u < 32; ++u) {
                float4 b = redx[u * 16 + lane16];
                sm.x += b.x; sm.y += b.y; sm.z += b.z; sm.w += b.w;
            }
            float invK = 1.f / 256.f;
            int c = lane16 * 4;
            float ar[4] = {sm.x * invK, sm.y * invK, sm.z * invK, sm.w * invK};
#pragma unroll
            for (int u = 0; u < 4; ++u) {
                x1rs[c + u]      = mr[u];
                x1rs[64 + c + u] = ar[u];
            }
        }
    }
    // ---- compact: gated selected rows -> shx rows 0..255 ----
    {
        int* nor = perm;                         // perm dead after score1
        __syncthreads();
        for (int i = t; i < NN; i += 1024) {
            int r = rnk[i];
            if (r < 256) nor[r] = i;
        }
        __syncthreads();
        float4 stash[4];
        int rr[4], cc[4];
#pragma unroll
        for (int u = 0; u < 4; ++u) {
            int idx = t + u * 1024;
            rr[u] = idx >> 4; cc[u] = idx & 15;
            int n = nor[rr[u]];
            float gt = tanhf(ssc[n]);
            float4 v = *(const float4*)&shx[n * 68 + cc[u] * 4];
            v.x *= gt; v.y *= gt; v.z *= gt; v.w *= gt;
            stash[u] = v;
        }
        __syncthreads();                          // all reads of h complete
#pragma unroll
        for (int u = 0; u < 4; ++u)
            *(float4*)&shx[rr[u] * 68 + cc[u] * 4] = stash[u];
        __syncthreads();
    }

    // ================= STAGE 2 (xn in shx rows 0..255) =================
    int2* lp2 = (int2*)&shx[256 * 68];           // rows 256-511 dead: pairs2 in LDS
    // ---- CSR2 (remap via stage1 rnk in LDS) ----
    for (int i = t; i < 256; i += 1024) { cnt[i] = 0; wsum[i] = 0.f; }
    __syncthreads();
    {
        const int4*   edst4 = (const int4*)(edst + e0);
        const int4*   esrc4 = (const int4*)(esrc + e0);
        const float4* eatt4 = (const float4*)(eatt + e0);
        int ed[8], es[8]; float ea[8];
#pragma unroll
        for (int c = 0; c < 2; ++c) {
            int ch = t + c * 1024;
            int4 dd = edst4[ch]; int4 ss = esrc4[ch]; float4 ww = eatt4[ch];
            ed[c*4+0]=dd.x; ed[c*4+1]=dd.y; ed[c*4+2]=dd.z; ed[c*4+3]=dd.w;
            es[c*4+0]=ss.x; es[c*4+1]=ss.y; es[c*4+2]=ss.z; es[c*4+3]=ss.w;
            ea[c*4+0]=ww.x; ea[c*4+1]=ww.y; ea[c*4+2]=ww.z; ea[c*4+3]=ww.w;
        }
#pragma unroll
        for (int j = 0; j < 8; ++j) {             // remap to stage-2 local ids
            int rd = rnk[ed[j] - nb1], rs = rnk[es[j] - nb1];
            ed[j] = (rd < 256) ? rd : -1;
            es[j] = (rs < 256) ? rs : -1;
        }
#pragma unroll
        for (int j = 0; j < 8; ++j) {
            if (ed[j] >= 0 && es[j] >= 0) {
                atomicAdd(&cnt[ed[j]], 1);
                atomicAdd(&wsum[ed[j]], ea[j]);
            }
        }
        __syncthreads();
        int wv = t >> 6;
        int xval = (t < 256) ? cnt[t] : 0;
        int xs = xval;
#pragma unroll
        for (int off = 1; off < 64; off <<= 1) {
            int v = __shfl_up(xs, off, 64);
            if (lane >= off) xs += v;
        }
        if (lane == 63) wtot[wv] = xs;
        __syncthreads();
        int woff = 0;
#pragma unroll
        for (int w = 0; w < 16; ++w) { int wt = wtot[w]; if (w < wv) woff += wt; }
        xs += woff;
        if (t < 256) {
            int st = xs - xval;
            rstl[t] = st;
            sdinv[t] = rsqrtf(wsum[t] + 1.0f);
            scn[t] = st;
        }
        __syncthreads();                          // rnk remap reads done above
        int slots[8]; float cf[8];
#pragma unroll
        for (int j = 0; j < 8; ++j) {
            slots[j] = -1;
            if (ed[j] >= 0 && es[j] >= 0) {
                cf[j] = sdinv[ed[j]] * ea[j] * sdinv[es[j]];
                slots[j] = atomicAdd(&scn[ed[j]], 1);
            }
        }
#pragma unroll
        for (int j = 0; j < 8; ++j)
            if (slots[j] >= 0)
                lp2[slots[j]] = make_int2(es[j], __float_as_int(cf[j]));
        for (int i = t; i < 256; i += 1024) rnk[i] = 0;
        if (t < 64) { sbw[t] = ((const float*)b2_4)[t]; hist[t] = 0; }
        __syncthreads();
    }
    // ---- GEMM2 (4 tiles, rows 0..255) ----
    {
        int q = t >> 8, tq = t & 255, rg = tq >> 4, cg = tq & 15;
        float4 a4[4];
        gemm_tile(shx, W2_4, q * 64, rg, cg, a4);
        __syncthreads();
        int row0 = q * 64;
        *(float4*)&shx[(row0 + rg * 4 + 0) * 68 + cg * 4] = a4[0];
        *(float4*)&shx[(row0 + rg * 4 + 1) * 68 + cg * 4] = a4[1];
        *(float4*)&shx[(row0 + rg * 4 + 2) * 68 + cg * 4] = a4[2];
        *(float4*)&shx[(row0 + rg * 4 + 3) * 68 + cg * 4] = a4[3];
    }
    __syncthreads();
    // ---- tail2: hist/perm ----
    for (int i = t; i < 256; i += 1024) atomicAdd(&hist[min(cnt[i], 63)], 1);
    __syncthreads();
    if (t < 64) {
        int v = hist[t], s = v;
#pragma unroll
        for (int off = 1; off < 64; off <<= 1) {
            int u = __shfl_up(s, off, 64);
            if (lane >= off) s += u;
        }
        hist[t] = s - v;
    }
    __syncthreads();
    for (int i = t; i < 256; i += 1024) {
        int pos = atomicAdd(&hist[min(cnt[i], 63)], 1);
        perm[pos] = i;
    }
    __syncthreads();
    // ---- conv2 (LPN=4, QF=4; pairs from LDS) ----
    {
        int idx2 = t >> 2, half = t & 3, fb = half * 4;
        int nl = perm[idx2];
        int st = rstl[nl], cn = cnt[nl];
        float di = sdinv[nl], dii = di * di;
        const int2* pb = lp2 + st;
        float4 acc[4];
#pragma unroll
        for (int c = 0; c < 4; ++c) {
            float4 xv = *(const float4*)&shx[nl * 68 + (fb + c) * 4];
            acc[c].x = fmaf(xv.x, dii, sbw[(fb + c) * 4 + 0]);
            acc[c].y = fmaf(xv.y, dii, sbw[(fb + c) * 4 + 1]);
            acc[c].z = fmaf(xv.z, dii, sbw[(fb + c) * 4 + 2]);
            acc[c].w = fmaf(xv.w, dii, sbw[(fb + c) * 4 + 3]);
        }
        int2 p0 = (cn > 0) ? pb[0] : make_int2(0, 0);
        int2 p1 = (cn > 1) ? pb[1] : make_int2(0, 0);
        for (int j = 0; j < cn; ++j) {
            int2 p2 = (j + 2 < cn) ? pb[j + 2] : make_int2(0, 0);
            float cfv = __int_as_float(p0.y);
            int   s   = p0.x;
#pragma unroll
            for (int c = 0; c < 4; ++c)
                acc[c] = f4fma(cfv, *(const float4*)&shx[s * 68 + (fb + c) * 4], acc[c]);
            p0 = p1; p1 = p2;
        }
#pragma unroll
        for (int c = 0; c < 4; ++c) {
            acc[c].x = fmaxf(acc[c].x, 0.f); acc[c].y = fmaxf(acc[c].y, 0.f);
            acc[c].z = fmaxf(acc[c].z, 0.f); acc[c].w = fmaxf(acc[c].w, 0.f);
        }
        __syncthreads();
#pragma unroll
        for (int c = 0; c < 4; ++c)
            *(float4*)&shx[nl * 68 + (fb + c) * 4] = acc[c];
    }
    __syncthreads();
    // ---- hp2 ----
    if (t < 512) {
        int wv8 = t >> 6, sub4 = (t >> 4) & 3;
        float4 w4 = wp2_4[lane16];
#pragma unroll
        for (int p = 0; p < 8; ++p) {
            int n2 = p * 32 + wv8 * 4 + sub4;
            float4 a = *(const float4*)&shx[n2 * 68 + lane16 * 4];
            float tt = a.x * w4.x + a.y * w4.y + a.z * w4.z + a.w * w4.w;
            tt += __shfl_xor(tt, 1, 64); tt += __shfl_xor(tt, 2, 64);
            tt += __shfl_xor(tt, 4, 64); tt += __shfl_xor(tt, 8, 64);
            if (lane16 == 0) shp[n2] = tt;
        }
    }
    __syncthreads();
    // ---- score2 ----
    if (t < 256) {
        int i = perm[t];
        int st = rstl[i], cn = cnt[i];
        float di = sdinv[i];
        const int2* pb = lp2 + st;
        float a = fmaf(shp[i], di * di, bp2[0]);
        int2 q0 = (cn > 0) ? pb[0] : make_int2(0, 0);
        int2 q1 = (cn > 1) ? pb[1] : make_int2(0, 0);
        for (int j = 0; j < cn; ++j) {
            int2 q2v = (j + 2 < cn) ? pb[j + 2] : make_int2(0, 0);
            a = fmaf(__int_as_float(q0.y), shp[q0.x], a);
            q0 = q1; q1 = q2v;
        }
        ssc[i] = a;
    }
    __syncthreads();
    // ---- rank2 (4 partials per node) ----
    {
        int part = t >> 8, i = t & 255;
        float si = ssc[i];
        int j0 = part * 64, rank = 0;
        for (int j = j0; j < j0 + 64; j += 4) {
            float4 sj = *(const float4*)&ssc[j];
            rank += (sj.x > si) || (sj.x == si && j     < i);
            rank += (sj.y > si) || (sj.y == si && j + 1 < i);
            rank += (sj.z > si) || (sj.z == si && j + 2 < i);
            rank += (sj.w > si) || (sj.w == si && j + 3 < i);
        }
        atomicAdd(&rnk[i], rank);
    }
    __syncthreads();
    // ---- readout2 + final out ----
    {
        float4 mx = make_float4(-3.402823466e38f, -3.402823466e38f, -3.402823466e38f, -3.402823466e38f);
        float4 sm = make_float4(0.f, 0.f, 0.f, 0.f);
        if (t < 512) {
            int wv8 = t >> 6, sub4 = (t >> 4) & 3;
#pragma unroll
            for (int p = 0; p < 8; ++p) {
                int n2 = p * 32 + wv8 * 4 + sub4;
                int r = rnk[n2];
                if (r < 128) {
                    float gt = tanhf(ssc[n2]);
                    float4 v = *(const float4*)&shx[n2 * 68 + lane16 * 4];
                    v.x *= gt; v.y *= gt; v.z *= gt; v.w *= gt;
                    mx.x = fmaxf(mx.x, v.x); mx.y = fmaxf(mx.y, v.y);
                    mx.z = fmaxf(mx.z, v.z); mx.w = fmaxf(mx.w, v.w);
                    sm.x += v.x; sm.y += v.y; sm.z += v.z; sm.w += v.w;
                }
            }
        }
        int grp = t >> 4;
        __syncthreads();
        if (t < 512) redx[grp * 16 + lane16] = mx;
        __syncthreads();
        float mr[4] = {0, 0, 0, 0};
        if (grp == 0) {
#pragma unroll
            for (int u = 1; u < 32; ++u) {
                float4 a = redx[u * 16 + lane16];
                mx.x = fmaxf(mx.x, a.x); mx.y = fmaxf(mx.y, a.y);
                mx.z = fmaxf(mx.z, a.z); mx.w = fmaxf(mx.w, a.w);
            }
            mr[0] = mx.x; mr[1] = mx.y; mr[2] = mx.z; mr[3] = mx.w;
        }
        __syncthreads();
        if (t < 512) redx[grp * 16 + lane16] = sm;
        __syncthreads();
        if (grp == 0) {
#pragma unroll
            for (int u = 1; u < 32; ++u) {
                float4 b = redx[u * 16 + lane16];
                sm.x += b.x; sm.y += b.y; sm.z += b.z; sm.w += b.w;
            }
            float invK = 1.f / 128.f;
            int c = lane16 * 4;
            float ar[4] = {sm.x * invK, sm.y * invK, sm.z * invK, sm.w * invK};
#pragma unroll
            for (int u = 0; u < 4; ++u) {
                out[g * 128 + c + u]      = 0.5f * (x1rs[c + u]      + mr[u]);
                out[g * 128 + 64 + c + u] = 0.5f * (x1rs[64 + c + u] + ar[u]);
            }
        }
    }
}

extern "C" void kernel_launch(void* const* d_in, const int* in_sizes, int n_in,
                              void* d_out, int out_size, void* d_ws, size_t ws_size,
                              hipStream_t stream) {
    const float* x    = (const float*)d_in[0];
    const float* eatt = (const float*)d_in[1];
    const float* W1   = (const float*)d_in[2];
    const float* b1   = (const float*)d_in[3];
    const float* Wp1  = (const float*)d_in[4];
    const float* bp1  = (const float*)d_in[5];
    const float* W2   = (const float*)d_in[6];
    const float* b2   = (const float*)d_in[7];
    const float* Wp2  = (const float*)d_in[8];
    const float* bp2  = (const float*)d_in[9];
    const int*   esrc = (const int*)d_in[10];
    const int*   edst = (const int*)d_in[11];
    float* out = (float*)d_out;

    int2* prs = (int2*)d_ws;                     // [NE] only workspace user

    mega_kernel<<<BG, 1024, 0, stream>>>(
        esrc, edst, eatt, prs, (const float4*)x,
        (const float4*)W1, (const float4*)b1, (const float4*)Wp1, bp1,
        (const float4*)W2, (const float4*)b2, (const float4*)Wp2, bp2,
        out);
}